// Round 7
// baseline (127.161 us; speedup 1.0000x reference)
//
#include <hip/hip_runtime.h>
#include <stdint.h>

// DVH global loss, MI355X.
// B=4 batches, N=2^21 voxels/batch, 500 bins over [0,75].
// loss = mean_{b,j} ( suffix_sum_{k>j}(hist_p[b]-hist_g[b])[k] / (maskcount_b+1e-6) )^2
// Only the DIFFERENCE histogram matters: d[i] = hist_p[i] - hist_g[i] (exact in ints).
//
// R1: device fence -> per-wave L2 writeback -> 201 us. Reverted.
// R2: fence-free last-block protocol, 512x1024, atomic drain -> 41.5 us kernel.
// R3: 4096x256 -> 117 us: drain atomics scale with block count. Few fat blocks.
// R4: per-block partial stores -> 1 MB single-block merge tail. Reverted.
// R5: 8-replica drain -> neutral. Main phase ~40 us vs ~16 us delivery floor.
// R6: sched_barrier(0) did NOT stop load sinking (VGPR 28->24, time flat):
//     loads are pure -> sunk at IR level before the scheduler runs.
// R7: force liveness with empty asm "+v" keep-alives on every payload
//     component (rule #17): real data deps -> loads can't sink past them.
//     All 12 loads issue back-to-back, staged vmcnt waits, then compute.
//     VERIFY: VGPR_Count must rise to ~56-72, else transform didn't take.

#define NBINS 500
#define NHIST 501          // searchsorted index c in [0,500]; c>=1 for d>=0
#define BATCH 4
#define NPB (1 << 21)      // elements per batch
#define VPB (NPB / 4)      // float4 per batch
#define THREADS 1024
#define BLOCKS_PER_BATCH 128
#define STRIDE (BLOCKS_PER_BATCH * THREADS)   // 131072 float4s; VPB/STRIDE == 4
#define TOTAL_BLOCKS (BLOCKS_PER_BATCH * BATCH)   // 512
#define REPS 8             // replica histograms per batch

// workspace layout (int32):
//   replica hists : [(b*REPS + r)*512 + i], i<512, r<8, b<4   (16384 ints)
//   maskcount     : [16384 + b]
//   done ctr      : [16388]
#define HIST_INTS (BATCH * REPS * 512)
#define MC_OFF HIST_INTS
#define CTR_OFF (HIST_INTS + 4)
#define ZERO_INTS (HIST_INTS + 8)

__device__ __forceinline__ int bin_of(float d) {
    // c = # of fp32 bins k*STEP that are <= d  (jnp.linspace(0,75,500),
    // searchsorted side='right'); d >= 0 guaranteed.
    const float STEP = 75.0f / 499.0f;
    const float INV  = 499.0f / 75.0f;
    int k = (int)(d * INV);
    if (k > 499) k = 499;
    if ((float)k * STEP > d) --k;
    else if (k < 499 && (float)(k + 1) * STEP <= d) ++k;
    if ((float)k * STEP > d) --k;   // safety second pass (k>=0 since bins[0]=0<=d)
    return k + 1;                   // in [1,500]
}

// Empty asm with "+v" on each component: creates a data dependency so the
// loads feeding these values CANNOT be sunk below this point (rule #17).
#define KEEP3(a, b, c) \
    asm volatile("" : "+v"(a.x), "+v"(a.y), "+v"(a.z), "+v"(a.w), \
                      "+v"(b.x), "+v"(b.y), "+v"(b.z), "+v"(b.w), \
                      "+v"(c.x), "+v"(c.y), "+v"(c.z), "+v"(c.w))

__global__ __launch_bounds__(THREADS) void dvh_fused_kernel(
        const float4* __restrict__ dp, const float4* __restrict__ dg,
        const float4* __restrict__ dm, int* __restrict__ ws,
        float* __restrict__ out) {
    __shared__ int shd[512];
    __shared__ unsigned int smc;
    __shared__ int lastflag;
    __shared__ int wtot[2][8];
    __shared__ float facc[16];

    const int b = blockIdx.y;
    const int t = threadIdx.x;
    if (t < 512) shd[t] = 0;
    if (t == 0) smc = 0u;
    __syncthreads();

    const size_t base = (size_t)b * VPB + blockIdx.x * THREADS + t;

    // Issue ALL 12 loads, then pin them live. Keep-alives are ordered among
    // themselves; all sit before any compute -> 12 loads in flight, staged
    // vmcnt waits, single latency exposure instead of 4.
    float4 mA = dm[base];              float4 pA = dp[base];              float4 gA = dg[base];
    float4 mB = dm[base + STRIDE];     float4 pB = dp[base + STRIDE];     float4 gB = dg[base + STRIDE];
    float4 mC = dm[base + 2 * STRIDE]; float4 pC = dp[base + 2 * STRIDE]; float4 gC = dg[base + 2 * STRIDE];
    float4 mD = dm[base + 3 * STRIDE]; float4 pD = dp[base + 3 * STRIDE]; float4 gD = dg[base + 3 * STRIDE];
    KEEP3(mA, pA, gA);
    KEEP3(mB, pB, gB);
    KEEP3(mC, pC, gC);
    KEEP3(mD, pD, gD);

    unsigned int myc = 0;
#define DO(mm, pp, gg) \
    if (mm != 0.0f) { atomicAdd(&shd[bin_of(pp)], 1); atomicAdd(&shd[bin_of(gg)], -1); ++myc; }
#define PROC(MM, PP, GG) \
    DO(MM.x, PP.x, GG.x) DO(MM.y, PP.y, GG.y) DO(MM.z, PP.z, GG.z) DO(MM.w, PP.w, GG.w)
    PROC(mA, pA, gA)
    PROC(mB, pB, gB)
    PROC(mC, pC, gC)
    PROC(mD, pD, gD)
#undef PROC
#undef DO

    if (myc) atomicAdd(&smc, myc);
    __syncthreads();

    // Drain into one of 8 replica histograms for this batch (R5-verified:
    // contention spread, 64 KB total merge for last block).
    {
        const int rep = blockIdx.x & (REPS - 1);
        int* dst = &ws[(b * REPS + rep) * 512];
        if (t < 512) {
            int v = shd[t];
            if (v) atomicAdd(&dst[t], v);
        }
    }
    if (t == 0 && smc) atomicAdd((unsigned int*)&ws[MC_OFF + b], smc);

    // ---- last-arriving-block protocol (fence-free; verified R2/R4/R5) ----
    asm volatile("s_waitcnt vmcnt(0)" ::: "memory");
    __syncthreads();
    if (t == 0) {
        unsigned int old = atomicAdd((unsigned int*)&ws[CTR_OFF], 1u);
        lastflag = (old == TOTAL_BLOCKS - 1) ? 1 : 0;
    }
    __syncthreads();
    if (!lastflag) return;

    // Last block: merge 8 replicas per batch (64 KB total), scan, suffix, square.
    // Thread layout: half h = t>>9 handles batches {2h, 2h+1}; bin j = t&511.
    const int lane = t & 63;
    const int w = t >> 6;          // global wave 0..15
    const int h = t >> 9;          // half 0/1
    const int j = t & 511;         // bin index within half
    const int wl = (t >> 6) & 7;   // wave within half 0..7
    float acc = 0.0f;

    #pragma unroll
    for (int bi = 0; bi < 2; ++bi) {
        const int bb = h * 2 + bi;
        // merge replicas (agent-scope loads bypass stale local cache lines)
        int s = 0;
        const int pb = (bb * REPS) * 512 + j;
        #pragma unroll
        for (int r = 0; r < REPS; ++r) {
            s += __hip_atomic_load(&ws[pb + r * 512],
                                   __ATOMIC_RELAXED, __HIP_MEMORY_SCOPE_AGENT);
        }
        // inclusive scan over the 512 threads of this half
        int v = s;
        #pragma unroll
        for (int off = 1; off < 64; off <<= 1) {
            int n = __shfl_up(v, off, 64);
            if (lane >= off) v += n;
        }
        if (lane == 63) wtot[h][wl] = v;
        __syncthreads();
        int offset = 0, total = 0;
        #pragma unroll
        for (int i = 0; i < 8; ++i) {
            int x = wtot[h][i];
            total += x;
            if (i < wl) offset += x;
        }
        const int prefix = v + offset;   // inclusive prefix over d[0..j]
        const unsigned int mc = __hip_atomic_load(
            (unsigned int*)&ws[MC_OFF + bb], __ATOMIC_RELAXED,
            __HIP_MEMORY_SCOPE_AGENT);
        const float denom = (float)mc + 1e-6f;
        if (j < NBINS) {
            // count_ge[j] diff = sum_{k>=j+1} d[k] = total - incl_prefix[j]
            const float diff = (float)(total - prefix) / denom;
            acc += diff * diff;
        }
        __syncthreads();   // before wtot reuse next iteration
    }

    // block reduction of acc
    #pragma unroll
    for (int off = 32; off > 0; off >>= 1) acc += __shfl_down(acc, off, 64);
    if (lane == 0) facc[w] = acc;
    __syncthreads();
    if (t == 0) {
        float ssum = 0.0f;
        #pragma unroll
        for (int i = 0; i < 16; ++i) ssum += facc[i];
        out[0] = ssum * (1.0f / (BATCH * NBINS));
    }
}

extern "C" void kernel_launch(void* const* d_in, const int* in_sizes, int n_in,
                              void* d_out, int out_size, void* d_ws, size_t ws_size,
                              hipStream_t stream) {
    const float4* dp = (const float4*)d_in[0];   // d_pred
    const float4* dg = (const float4*)d_in[1];   // d_gt
    const float4* dm = (const float4*)d_in[2];   // mask
    int* ws = (int*)d_ws;

    hipMemsetAsync(ws, 0, ZERO_INTS * sizeof(int), stream);

    dim3 grid(BLOCKS_PER_BATCH, BATCH);
    dvh_fused_kernel<<<grid, dim3(THREADS), 0, stream>>>(dp, dg, dm, ws, (float*)d_out);
}

// Round 8
// 125.210 us; speedup vs baseline: 1.0156x; 1.0156x over previous
//
#include <hip/hip_runtime.h>
#include <stdint.h>

// DVH global loss, MI355X.
// B=4 batches, N=2^21 voxels/batch, 500 bins over [0,75].
// loss = mean_{b,j} ( suffix_sum_{k>j}(hist_p[b]-hist_g[b])[k] / (maskcount_b+1e-6) )^2
// Only the DIFFERENCE histogram matters: d[i] = hist_p[i] - hist_g[i] (exact in ints).
//
// R1: device fence -> per-wave L2 writeback -> 201 us. Reverted.
// R2: fence-free last-block protocol, 512x1024, atomic drain -> 41.5 us kernel.
// R3: 4096x256 -> 117 us: drain atomics scale with block count.
// R4: per-block partial stores -> 1 MB single-block merge tail. Reverted.
// R5: 8-replica drain -> neutral. Main phase ~40 us vs ~16 us delivery floor.
// R6: sched_barrier(0) did not stop load sinking (VGPR 28->24, flat).
// R7: asm "+v" keep-alives also defeated (VGPR 28, flat): computes legally
//     interleave between the keep markers -> serial {load3,wait,compute}x4.
// R8: own the pipeline end-to-end in inline asm (T4 counted-vmcnt):
//     9 asm global_load_dwordx4 (volatile, ordered, un-sinkable) ->
//     s_waitcnt vmcnt(6) + sched_barrier(0) -> PROC(A) -> issue D ->
//     vmcnt(6)/PROC(B) -> vmcnt(3)/PROC(C) -> vmcnt(0)/PROC(D).
//     SGPR-base + u32 voffset addressing keeps peak VGPR ~56 (<64 cliff).
//     VERIFY: VGPR_Count must land ~52-64.

#define NBINS 500
#define NHIST 501          // searchsorted index c in [0,500]; c>=1 for d>=0
#define BATCH 4
#define NPB (1 << 21)      // elements per batch
#define VPB (NPB / 4)      // float4 per batch
#define THREADS 1024
#define BLOCKS_PER_BATCH 128
#define STRIDE (BLOCKS_PER_BATCH * THREADS)   // 131072 float4s; VPB/STRIDE == 4
#define TOTAL_BLOCKS (BLOCKS_PER_BATCH * BATCH)   // 512
#define REPS 8             // replica histograms per batch

// workspace layout (int32):
//   replica hists : [(b*REPS + r)*512 + i], i<512, r<8, b<4   (16384 ints)
//   maskcount     : [16384 + b]
//   done ctr      : [16388]
#define HIST_INTS (BATCH * REPS * 512)
#define MC_OFF HIST_INTS
#define CTR_OFF (HIST_INTS + 4)
#define ZERO_INTS (HIST_INTS + 8)

__device__ __forceinline__ int bin_of(float d) {
    // c = # of fp32 bins k*STEP that are <= d  (jnp.linspace(0,75,500),
    // searchsorted side='right'); d >= 0 guaranteed.
    const float STEP = 75.0f / 499.0f;
    const float INV  = 499.0f / 75.0f;
    int k = (int)(d * INV);
    if (k > 499) k = 499;
    if ((float)k * STEP > d) --k;
    else if (k < 499 && (float)(k + 1) * STEP <= d) ++k;
    if ((float)k * STEP > d) --k;   // safety second pass (k>=0 since bins[0]=0<=d)
    return k + 1;                   // in [1,500]
}

// Inline-asm 16B load: volatile => cannot be sunk, deleted, or reordered
// against other volatile asm. SGPR base + 32-bit VGPR byte-offset form.
__device__ __forceinline__ float4 ldx4(const float4* __restrict__ sbase,
                                       unsigned voff) {
    float4 r;
    asm volatile("global_load_dwordx4 %0, %1, %2"
                 : "=&v"(r)
                 : "v"(voff), "s"(sbase));
    return r;
}

// Counted wait + scheduler fence (rule #18: SB(0) right after the waitcnt so
// no consumer is hoisted above it; "memory" keeps LDS atomics below).
#define WAITSB(n) do { \
    asm volatile("s_waitcnt vmcnt(" #n ")" ::: "memory"); \
    __builtin_amdgcn_sched_barrier(0); \
} while (0)

__global__ __launch_bounds__(THREADS) void dvh_fused_kernel(
        const float4* __restrict__ dp, const float4* __restrict__ dg,
        const float4* __restrict__ dm, int* __restrict__ ws,
        float* __restrict__ out) {
    __shared__ int shd[512];
    __shared__ unsigned int smc;
    __shared__ int lastflag;
    __shared__ int wtot[2][8];
    __shared__ float facc[16];

    const int b = blockIdx.y;
    const int t = threadIdx.x;
    if (t < 512) shd[t] = 0;
    if (t == 0) smc = 0u;
    __syncthreads();

    // byte offsets (u32): elem idx <= 2^21, *16B = 32 MB fits easily
    const unsigned e0 = (unsigned)(b * VPB + blockIdx.x * THREADS + t);
    const unsigned o0 = e0 * 16u;
    const unsigned o1 = o0 + (unsigned)STRIDE * 16u;
    const unsigned o2 = o1 + (unsigned)STRIDE * 16u;
    const unsigned o3 = o2 + (unsigned)STRIDE * 16u;

    // ---- counted-vmcnt pipeline: issue chunks A,B,C (9 loads in flight) ----
    float4 mA = ldx4(dm, o0); float4 pA = ldx4(dp, o0); float4 gA = ldx4(dg, o0);
    float4 mB = ldx4(dm, o1); float4 pB = ldx4(dp, o1); float4 gB = ldx4(dg, o1);
    float4 mC = ldx4(dm, o2); float4 pC = ldx4(dp, o2); float4 gC = ldx4(dg, o2);

    unsigned int myc = 0;
#define DO(mm, pp, gg) \
    if (mm != 0.0f) { atomicAdd(&shd[bin_of(pp)], 1); atomicAdd(&shd[bin_of(gg)], -1); ++myc; }
#define PROC(MM, PP, GG) \
    DO(MM.x, PP.x, GG.x) DO(MM.y, PP.y, GG.y) DO(MM.z, PP.z, GG.z) DO(MM.w, PP.w, GG.w)

    WAITSB(6);               // chunk A landed; B,C still in flight
    PROC(mA, pA, gA)
    // issue chunk D while B,C stream
    float4 mD = ldx4(dm, o3); float4 pD = ldx4(dp, o3); float4 gD = ldx4(dg, o3);
    WAITSB(6);               // chunk B landed; C,D in flight
    PROC(mB, pB, gB)
    WAITSB(3);               // chunk C landed; D in flight
    PROC(mC, pC, gC)
    WAITSB(0);               // chunk D landed
    PROC(mD, pD, gD)
#undef PROC
#undef DO

    if (myc) atomicAdd(&smc, myc);
    __syncthreads();

    // Drain into one of 8 replica histograms for this batch (R5-verified:
    // contention spread, 64 KB total merge for last block).
    {
        const int rep = blockIdx.x & (REPS - 1);
        int* dst = &ws[(b * REPS + rep) * 512];
        if (t < 512) {
            int v = shd[t];
            if (v) atomicAdd(&dst[t], v);
        }
    }
    if (t == 0 && smc) atomicAdd((unsigned int*)&ws[MC_OFF + b], smc);

    // ---- last-arriving-block protocol (fence-free; verified R2/R4/R5) ----
    asm volatile("s_waitcnt vmcnt(0)" ::: "memory");
    __syncthreads();
    if (t == 0) {
        unsigned int old = atomicAdd((unsigned int*)&ws[CTR_OFF], 1u);
        lastflag = (old == TOTAL_BLOCKS - 1) ? 1 : 0;
    }
    __syncthreads();
    if (!lastflag) return;

    // Last block: merge 8 replicas per batch (64 KB total), scan, suffix, square.
    // Thread layout: half h = t>>9 handles batches {2h, 2h+1}; bin j = t&511.
    const int lane = t & 63;
    const int w = t >> 6;          // global wave 0..15
    const int h = t >> 9;          // half 0/1
    const int j = t & 511;         // bin index within half
    const int wl = (t >> 6) & 7;   // wave within half 0..7
    float acc = 0.0f;

    #pragma unroll
    for (int bi = 0; bi < 2; ++bi) {
        const int bb = h * 2 + bi;
        // merge replicas (agent-scope loads bypass stale local cache lines)
        int s = 0;
        const int pb = (bb * REPS) * 512 + j;
        #pragma unroll
        for (int r = 0; r < REPS; ++r) {
            s += __hip_atomic_load(&ws[pb + r * 512],
                                   __ATOMIC_RELAXED, __HIP_MEMORY_SCOPE_AGENT);
        }
        // inclusive scan over the 512 threads of this half
        int v = s;
        #pragma unroll
        for (int off = 1; off < 64; off <<= 1) {
            int n = __shfl_up(v, off, 64);
            if (lane >= off) v += n;
        }
        if (lane == 63) wtot[h][wl] = v;
        __syncthreads();
        int offset = 0, total = 0;
        #pragma unroll
        for (int i = 0; i < 8; ++i) {
            int x = wtot[h][i];
            total += x;
            if (i < wl) offset += x;
        }
        const int prefix = v + offset;   // inclusive prefix over d[0..j]
        const unsigned int mc = __hip_atomic_load(
            (unsigned int*)&ws[MC_OFF + bb], __ATOMIC_RELAXED,
            __HIP_MEMORY_SCOPE_AGENT);
        const float denom = (float)mc + 1e-6f;
        if (j < NBINS) {
            // count_ge[j] diff = sum_{k>=j+1} d[k] = total - incl_prefix[j]
            const float diff = (float)(total - prefix) / denom;
            acc += diff * diff;
        }
        __syncthreads();   // before wtot reuse next iteration
    }

    // block reduction of acc
    #pragma unroll
    for (int off = 32; off > 0; off >>= 1) acc += __shfl_down(acc, off, 64);
    if (lane == 0) facc[w] = acc;
    __syncthreads();
    if (t == 0) {
        float ssum = 0.0f;
        #pragma unroll
        for (int i = 0; i < 16; ++i) ssum += facc[i];
        out[0] = ssum * (1.0f / (BATCH * NBINS));
    }
}

extern "C" void kernel_launch(void* const* d_in, const int* in_sizes, int n_in,
                              void* d_out, int out_size, void* d_ws, size_t ws_size,
                              hipStream_t stream) {
    const float4* dp = (const float4*)d_in[0];   // d_pred
    const float4* dg = (const float4*)d_in[1];   // d_gt
    const float4* dm = (const float4*)d_in[2];   // mask
    int* ws = (int*)d_ws;

    hipMemsetAsync(ws, 0, ZERO_INTS * sizeof(int), stream);

    dim3 grid(BLOCKS_PER_BATCH, BATCH);
    dvh_fused_kernel<<<grid, dim3(THREADS), 0, stream>>>(dp, dg, dm, ws, (float*)d_out);
}